// Round 4
// baseline (11961.991 us; speedup 1.0000x reference)
//
#include <hip/hip_runtime.h>
#include <hip/hip_bf16.h>
#include <stdint.h>

// ---------------------------------------------------------------------------
// Peephole LSTM, SEQ=512, B=64, I=H=1024.  Persistent-kernel, 256 blocks.
// Round-13: R12 (reg-pinned weights, 8.03ms) + DRAIN-FREE tagged exchange.
//  * Chain accounting: 2 exchanges/step x ~3.5 L3-RTs each (drain + flag
//    detect + payload pull).  R10 proved tagged-payload semantics correct
//    (passed; failed only on poll-traffic).  R11/12 proved the direct-poll
//    flag barrier.  This round combines the VERIFIED halves:
//      - flags remain the wait gate (cheap 64-lane poll, payload read once)
//      - payload carries embedded monotone tags (8B units: payload,tag)
//      - bar_arrive drops s_waitcnt vmcnt(0): flag no longer promises
//        payload visibility; the consumer validates embedded tags after
//        detect and re-reads stale chunks (empirically ~never: payload
//        stores precede the flag by issue order + a full detect RT).
//    => removes 1 RT per exchange (~3us/step).
//  * Single-slot h/c buffers, monotone tags: producer overwrites tag T
//    with T+1 only after every consumer used T (full dependency chain
//    through all blocks) -- R10-verified.
//  * x(t+1) staging moved into the (empty) c-exchange gap; sx is dead
//    there, and bar_wait(c)'s __syncthreads orders writes vs t+1 reads.
//  * Startup c0 tile now converted fp32->bf16 in-kernel (drops cbf buf).
//  * Everything else byte-identical to R12 (verified).
// ---------------------------------------------------------------------------

typedef __attribute__((ext_vector_type(8))) short short8;
typedef __attribute__((ext_vector_type(4))) float f32x4;
typedef __attribute__((ext_vector_type(4))) unsigned int uint4v;
typedef __attribute__((ext_vector_type(2))) unsigned int uint2v;

#define OFF_WB   25165824u   // WA: 64cg*4g*96kc*64l*8e bf16
#define OFF_HT   27262976u   // WB: 64*4*8*64*8 bf16 = 2097152
#define OFF_CT   27525120u   // hT: 64row*512pair*8B = 262144
#define OFF_BAR  27787264u   // cT: 262144
#define WS_NEED  27803648u   // bar: 16 KB

__device__ __forceinline__ short bfc(float f) {
  __hip_bfloat16 h = __float2bfloat16(f);
  return *reinterpret_cast<short*>(&h);
}
__device__ __forceinline__ unsigned pk2(float a, float b) {
  __hip_bfloat16 ha = __float2bfloat16(a), hb = __float2bfloat16(b);
  unsigned short ua = *reinterpret_cast<unsigned short*>(&ha);
  unsigned short ub = *reinterpret_cast<unsigned short*>(&hb);
  return (unsigned)ua | ((unsigned)ub << 16);
}
__device__ __forceinline__ float sig_fast(float v) {
  return __fdividef(1.f, 1.f + __expf(-v));
}
__device__ __forceinline__ float tanh_fast(float v) {
  float a = fabsf(v);
  float e = __expf(-2.f * a);
  float t = (1.f - e) * __fdividef(1.f, 1.f + e);
  return copysignf(t, v);
}

// ---- L1+L2-bypassing accesses (coherent at L3 across XCDs) ----
__device__ __forceinline__ uint4v ldg_sc(const void* p) {
  uint4v r;
  asm volatile("global_load_dwordx4 %0, %1, off sc0 sc1" : "=v"(r) : "v"(p));
  return r;
}
__device__ __forceinline__ unsigned poll_sc(const unsigned* p) {
  unsigned r;
  asm volatile("global_load_dword %0, %1, off sc0 sc1\n\ts_waitcnt vmcnt(0)"
               : "=v"(r) : "v"(p) : "memory");
  return r;
}
__device__ __forceinline__ void stg_u32_sc(unsigned* p, unsigned v) {
  asm volatile("global_store_dword %0, %1, off sc0 sc1" :: "v"(p), "v"(v) : "memory");
}
__device__ __forceinline__ void stg_u64_sc(void* p, unsigned lo, unsigned hi) {
  uint2v v; v.x = lo; v.y = hi;
  asm volatile("global_store_dwordx2 %0, %1, off sc0 sc1" :: "v"(p), "v"(v) : "memory");
}

// ---- direct-poll barrier (per 64-block rowgroup), DRAIN-FREE arrive ----
// flag dword idx: grp*1024 + memb*16   (64 B spacing, 4 KB per group)
__device__ __forceinline__ void bar_arrive(unsigned* bar, int grp, int memb, unsigned r) {
  __syncthreads();                     // all waves ISSUED their payload stores
  if (threadIdx.x == 0) stg_u32_sc(bar + grp * 1024 + memb * 16, r);
}
__device__ __forceinline__ void bar_wait(unsigned* bar, int grp, unsigned r) {
  if (threadIdx.x < 64) {
    const unsigned* p = bar + grp * 1024 + threadIdx.x * 16;
    unsigned spins = 0;
    for (;;) {
      unsigned v = poll_sc(p);
      if (__all((int)(v >= r))) break;
      __builtin_amdgcn_s_sleep(1);
      if (++spins > (1u << 18)) break;               // failsafe: fail loud
    }
  }
  __syncthreads();
  __builtin_amdgcn_sched_barrier(0);
}

// ---------------------------------------------------------------------------
// prep: pack weights into lane-ordered bf16 fragments + init tagged state.
// WA slot ((cg*4+g)*96+kc)*64+l holds W_g[j=cg*16+(l&15)][kc*32+8*(l>>4)+e]
// (kc 0..31 = x, 32..63 = h, 64..95 = c; gates 2,3 only kc<64).
// WB slot ((cg*4+v)*8+kc)*64+l holds Wo[j][2048 + v*256+kc*32+8*(l>>4)+e].
// hT unit u (row R=u>>9, pair p=u&511): (pk2(h0[R*1024+2p..]), tag 0).
// cT zero (tag 0; first write at t=0 carries tag 1).  bar zero.
// ---------------------------------------------------------------------------
#define Z0 1310720LL
#define Z1 131072LL
#define Z2 32768LL
#define Z3 32768LL
#define Z4 4096LL

__global__ __launch_bounds__(256)
void prep_kernel(const float* __restrict__ h0, const float* __restrict__ c0,
                 const float* __restrict__ Ww, const float* __restrict__ Wf,
                 const float* __restrict__ Wc, const float* __restrict__ Wo,
                 char* __restrict__ ws) {
  __hip_bfloat16* WA = (__hip_bfloat16*)ws;
  __hip_bfloat16* WB = (__hip_bfloat16*)(ws + OFF_WB);
  unsigned long long* hT = (unsigned long long*)(ws + OFF_HT);
  unsigned long long* cT = (unsigned long long*)(ws + OFF_CT);
  unsigned*          bar = (unsigned*)(ws + OFF_BAR);

  const long long total = Z0 + Z1 + Z2 + Z3 + Z4;
  for (long long idx = (long long)blockIdx.x * 256 + threadIdx.x; idx < total;
       idx += (long long)gridDim.x * 256) {
    if (idx < Z0) {
      int l  = (int)(idx & 63);
      int s  = (int)((idx >> 6) % 320);
      int cg = (int)(idx / (320 * 64));
      int g, kc;
      if (s < 96)       { g = 0; kc = s; }
      else if (s < 192) { g = 1; kc = s - 96; }
      else if (s < 256) { g = 2; kc = s - 192; }
      else              { g = 3; kc = s - 256; }
      int j  = cg * 16 + (l & 15);
      int kb = kc * 32 + ((l >> 4) << 3);
      const float* W; int rl;
      if (g == 0)      { W = Ww; rl = 3072; }
      else if (g == 1) { W = Wf; rl = 3072; }
      else if (g == 2) { W = Wc; rl = 2048; }
      else             { W = Wo; rl = 3072; }
      const float* src = W + (size_t)j * rl + kb;
      __hip_bfloat16* dst = WA + ((((size_t)cg * 4 + g) * 96 + kc) * 64 + l) * 8;
#pragma unroll
      for (int e = 0; e < 8; ++e) dst[e] = __float2bfloat16(src[e]);
    } else if (idx < Z0 + Z1) {
      long long q = idx - Z0;
      int l  = (int)(q & 63);
      int kc = (int)((q >> 6) & 7);
      int v  = (int)((q >> 9) & 3);
      int cg = (int)(q >> 11);
      int j  = cg * 16 + (l & 15);
      int k  = 2048 + v * 256 + kc * 32 + ((l >> 4) << 3);
      const float* src = Wo + (size_t)j * 3072 + k;
      __hip_bfloat16* dst = WB + ((((size_t)cg * 4 + v) * 8 + kc) * 64 + l) * 8;
#pragma unroll
      for (int e = 0; e < 8; ++e) dst[e] = __float2bfloat16(src[e]);
    } else if (idx < Z0 + Z1 + Z2) {
      int u = (int)(idx - (Z0 + Z1));
      const float* s = h0 + (size_t)(u >> 9) * 1024 + 2 * (u & 511);
      hT[u] = (unsigned long long)pk2(s[0], s[1]);   // payload lo, tag 0 hi
    } else if (idx < Z0 + Z1 + Z2 + Z3) {
      int u = (int)(idx - (Z0 + Z1 + Z2));
      cT[u] = 0ull;
    } else {
      int i = (int)(idx - (Z0 + Z1 + Z2 + Z3));
      bar[i] = 0u;
    }
  }
}

// ---------------------------------------------------------------------------
// main persistent kernel
// ---------------------------------------------------------------------------
__global__ __launch_bounds__(256, 1)
void lstm_kernel(const float* __restrict__ x,  const float* __restrict__ c0,
                 const float* __restrict__ bw, const float* __restrict__ bfg,
                 const float* __restrict__ bc, const float* __restrict__ bo,
                 float* __restrict__ out, char* __restrict__ ws) {
  char*     hT  = ws + OFF_HT;
  char*     cT  = ws + OFF_CT;
  unsigned* bar = (unsigned*)(ws + OFF_BAR);

  const int tid  = threadIdx.x;
  const int l    = tid & 63;
  const int wv   = tid >> 6;                         // wave = gate (A) / K-split (B)
  const int b    = blockIdx.x;
  const int cg   = ((b & 7) << 3) | ((b >> 3) & 7);  // XCD-partitioned col-group
  const int grp  = b >> 6;                           // batch row-group (0..3)
  const int memb = b & 63;
  const int col  = l & 15;
  const int kg   = l >> 4;
  const int row16 = col;                             // A-frag row within tile
  const int srow  = row16 & 7;                       // LDS swizzle key
  const int j    = (cg << 4) + col;

  const float* bptr = (wv == 0) ? bw : (wv == 1) ? bfg : (wv == 2) ? bc : bo;
  const float bias = bptr[j];

  const short8* BW = (const short8*)ws + ((size_t)(cg * 4 + wv)) * 96 * 64 + l;
  const short8* BO = (const short8*)(ws + OFF_WB) + ((size_t)(cg * 4 + wv)) * 8 * 64 + l;

  __shared__ __align__(16) char sx[32768];   // x tile  [16][1024] bf16, swizzled
  __shared__ __align__(16) char sh[32768];   // h tile
  __shared__ __align__(16) char sc_[32768];  // c tile (carried across steps)
  __shared__ float lds[5][16][17];

  // combine mapping: tid<128 owns (crow, 2 cols)
  const int crow = tid >> 3;
  const int cpr  = tid & 7;
  const int coff = ((grp * 16 + crow) << 10) + (cg << 4) + 2 * cpr;
  float c_reg0 = 0.f, c_reg1 = 0.f;
  if (tid < 128) { c_reg0 = c0[coff]; c_reg1 = c0[coff + 1]; }
  // tagged unit owned by this combiner: unit = (grp*16+crow)*512 + cg*8 + cpr
  char* hUnit = hT + ((size_t)(grp * 16 + crow) * 512 + (size_t)cg * 8 + cpr) * 8;
  char* cUnit = cT + ((size_t)(grp * 16 + crow) * 512 + (size_t)cg * 8 + cpr) * 8;

  // ---- startup: stage c0 tile fp32->bf16 -> swizzled sc_ once ----
  {
    const float* cs = c0 + (size_t)grp * 16384;
#pragma unroll
    for (int i = 0; i < 8; ++i) {
      int q = i * 256 + tid;
      const float* s = cs + q * 8;
      float4 f0 = *(const float4*)s;
      float4 f1 = *(const float4*)(s + 4);
      short8 v;
      v[0] = bfc(f0.x); v[1] = bfc(f0.y); v[2] = bfc(f0.z); v[3] = bfc(f0.w);
      v[4] = bfc(f1.x); v[5] = bfc(f1.y); v[6] = bfc(f1.z); v[7] = bfc(f1.w);
      int rw = q >> 7, kb = (q & 127) ^ (rw & 7);
      *(short8*)(sc_ + rw * 2048 + (kb << 4)) = v;
    }
  }
  // ---- startup: stage x(0) tile (consumed at loop top t=0) ----
  {
    const float* xs = x + (size_t)grp * 16384;
#pragma unroll
    for (int i = 0; i < 8; ++i) {
      int q = i * 256 + tid;
      const float* s = xs + q * 8;
      float4 f0 = *(const float4*)s;
      float4 f1 = *(const float4*)(s + 4);
      short8 v;
      v[0] = bfc(f0.x); v[1] = bfc(f0.y); v[2] = bfc(f0.z); v[3] = bfc(f0.w);
      v[4] = bfc(f1.x); v[5] = bfc(f1.y); v[6] = bfc(f1.z); v[7] = bfc(f1.w);
      int rw = q >> 7, kb = (q & 127) ^ (rw & 7);
      *(short8*)(sx + rw * 2048 + (kb << 4)) = v;
    }
  }

  // ---- pin recurrent-path weight fragments in registers (loop-invariant) ----
  short8 WH[32];
#pragma unroll
  for (int f = 0; f < 32; ++f) WH[f] = BW[(size_t)(32 + f) * 64];
  short8 WBo[8];
#pragma unroll
  for (int k = 0; k < 8; ++k) WBo[k] = BO[(size_t)k * 64];

  __syncthreads();                     // x(0)/sc_ staging visible block-wide

  for (int t = 0; t < 512; ++t) {
    f32x4 acc[4];
#pragma unroll
    for (int u = 0; u < 4; ++u) acc[u] = (f32x4){0.f, 0.f, 0.f, 0.f};

    // ---- phase A, x part (sx staged in previous iteration / startup) ----
#pragma unroll
    for (int kc = 0; kc < 8; ++kc)
#pragma unroll
      for (int u = 0; u < 4; ++u) {
        int f = kc * 4 + u;
        short8 a = *(const short8*)(sx + row16 * 2048 + ((((f << 2) + kg) ^ srow) << 4));
        acc[u] = __builtin_amdgcn_mfma_f32_16x16x32_bf16(a, BW[(size_t)f * 64], acc[u], 0, 0, 0);
      }

    bar_wait(bar, grp, 2u * t);          // h(t-1) flags posted

    // ---- tagged h load + validate + extract -> swizzled sh ----
    {
      const char* hbase = hT + (size_t)grp * 65536;
      const unsigned hwant = (unsigned)t;          // h(t-1) carries tag t
      uint4v ha[8], hb2[8];
#pragma unroll
      for (int i = 0; i < 8; ++i) {
        const char* p = hbase + (size_t)(i * 256 + tid) * 32;
        ha[i]  = ldg_sc(p);
        hb2[i] = ldg_sc(p + 16);
      }
      unsigned bad = 255u, spins = 0;
      for (;;) {
        asm volatile("s_waitcnt vmcnt(0)" ::: "memory");
        __builtin_amdgcn_sched_barrier(0);
#pragma unroll
        for (int i = 0; i < 8; ++i) if (bad & (1u << i)) {
          if (ha[i].y == hwant && ha[i].w == hwant &&
              hb2[i].y == hwant && hb2[i].w == hwant)
            bad &= ~(1u << i);
        }
        if (!bad) break;
        if (++spins > (1u << 16)) break;             // failsafe: fail loud
#pragma unroll
        for (int i = 0; i < 8; ++i) if (bad & (1u << i)) {
          const char* p = hbase + (size_t)(i * 256 + tid) * 32;
          ha[i]  = ldg_sc(p);
          hb2[i] = ldg_sc(p + 16);
        }
      }
      __builtin_amdgcn_sched_barrier(0);
#pragma unroll
      for (int i = 0; i < 8; ++i) {
        int q = i * 256 + tid;
        int rw = q >> 7, kb = (q & 127) ^ (rw & 7);
        uint4v pv = {ha[i].x, ha[i].z, hb2[i].x, hb2[i].z};
        *(uint4v*)(sh + rw * 2048 + (kb << 4)) = pv;
      }
    }
    __syncthreads();

    // ---- phase A, h part (all gates) — register-pinned fragments ----
#pragma unroll
    for (int kc = 0; kc < 8; ++kc)
#pragma unroll
      for (int u = 0; u < 4; ++u) {
        int f = kc * 4 + u;
        short8 a = *(const short8*)(sh + row16 * 2048 + ((((f << 2) + kg) ^ srow) << 4));
        acc[u] = __builtin_amdgcn_mfma_f32_16x16x32_bf16(a, WH[f], acc[u], 0, 0, 0);
      }
    // ---- phase A, c part (write & forget gates) — sc_ carries c(t-1) ----
    if (wv < 2) {
#pragma unroll
      for (int kc = 0; kc < 8; ++kc)
#pragma unroll
        for (int u = 0; u < 4; ++u) {
          int f = kc * 4 + u;
          short8 a = *(const short8*)(sc_ + row16 * 2048 + ((((f << 2) + kg) ^ srow) << 4));
          acc[u] = __builtin_amdgcn_mfma_f32_16x16x32_bf16(a, BW[(size_t)(64 + f) * 64], acc[u], 0, 0, 0);
        }
    }
    {
      const int dbuf = (wv == 3) ? 4 : wv;
#pragma unroll
      for (int i = 0; i < 4; ++i)
        lds[dbuf][kg * 4 + i][col] = acc[0][i] + acc[1][i] + acc[2][i] + acc[3][i] + bias;
    }
    __syncthreads();

    // ---- c_new combine (tid<128: 2 elems each); tagged store, no drain ----
    if (tid < 128) {
      float aw0 = lds[0][crow][2 * cpr], aw1 = lds[0][crow][2 * cpr + 1];
      float af0 = lds[1][crow][2 * cpr], af1 = lds[1][crow][2 * cpr + 1];
      float ag0 = lds[2][crow][2 * cpr], ag1 = lds[2][crow][2 * cpr + 1];
      float cn0 = sig_fast(af0) * c_reg0 + sig_fast(aw0) * tanh_fast(ag0);
      float cn1 = sig_fast(af1) * c_reg1 + sig_fast(aw1) * tanh_fast(ag1);
      c_reg0 = cn0; c_reg1 = cn1;
      stg_u64_sc(cUnit, pk2(cn0, cn1), (unsigned)t + 1u);
    }
    bar_arrive(bar, grp, memb, 2u * t + 1u);

    // ---- fill the c-exchange gap: stage x(t+1) (sx is dead here) ----
    if (t < 511) {
      const float* xs = x + (((size_t)t + 1) << 16) + (size_t)grp * 16384;
#pragma unroll
      for (int i = 0; i < 8; ++i) {
        int q = i * 256 + tid;
        const float* s = xs + q * 8;
        float4 f0 = *(const float4*)s;
        float4 f1 = *(const float4*)(s + 4);
        short8 v;
        v[0] = bfc(f0.x); v[1] = bfc(f0.y); v[2] = bfc(f0.z); v[3] = bfc(f0.w);
        v[4] = bfc(f1.x); v[5] = bfc(f1.y); v[6] = bfc(f1.z); v[7] = bfc(f1.w);
        int rw = q >> 7, kb = (q & 127) ^ (rw & 7);
        *(short8*)(sx + rw * 2048 + (kb << 4)) = v;
      }
    }

    bar_wait(bar, grp, 2u * t + 1u);     // c_new flags posted

    // ---- phase B: tagged c load + validate; o += c_new @ Woc^T; carry ----
    {
      const char* cbp = cT + (size_t)grp * 65536 + (size_t)row16 * 4096 +
                        (size_t)wv * 1024 + (size_t)kg * 32;
      const unsigned cwant = (unsigned)t + 1u;
      uint4v ca[8], cb2[8];
#pragma unroll
      for (int i = 0; i < 8; ++i) {
        ca[i]  = ldg_sc(cbp + (size_t)i * 128);
        cb2[i] = ldg_sc(cbp + (size_t)i * 128 + 16);
      }
      unsigned bad = 255u, spins = 0;
      for (;;) {
        asm volatile("s_waitcnt vmcnt(0)" ::: "memory");
        __builtin_amdgcn_sched_barrier(0);
#pragma unroll
        for (int i = 0; i < 8; ++i) if (bad & (1u << i)) {
          if (ca[i].y == cwant && ca[i].w == cwant &&
              cb2[i].y == cwant && cb2[i].w == cwant)
            bad &= ~(1u << i);
        }
        if (!bad) break;
        if (++spins > (1u << 16)) break;             // failsafe: fail loud
#pragma unroll
        for (int i = 0; i < 8; ++i) if (bad & (1u << i)) {
          ca[i]  = ldg_sc(cbp + (size_t)i * 128);
          cb2[i] = ldg_sc(cbp + (size_t)i * 128 + 16);
        }
      }
      __builtin_amdgcn_sched_barrier(0);

      f32x4 a0 = {0.f, 0.f, 0.f, 0.f}, a1 = {0.f, 0.f, 0.f, 0.f};
      const int ub = wv * 32 + kg;
#pragma unroll
      for (int kcc = 0; kcc < 8; ++kcc) {
        uint4v pv = {ca[kcc].x, ca[kcc].z, cb2[kcc].x, cb2[kcc].z};
        short8 a = __builtin_bit_cast(short8, pv);
        if (kcc & 1) a1 = __builtin_amdgcn_mfma_f32_16x16x32_bf16(a, WBo[kcc], a1, 0, 0, 0);
        else         a0 = __builtin_amdgcn_mfma_f32_16x16x32_bf16(a, WBo[kcc], a0, 0, 0, 0);
        // carry write: units u = wv*32 + kg + kcc*4 cover 0..127 bijectively
        *(uint4v*)(sc_ + row16 * 2048 + (((ub + kcc * 4) ^ srow) << 4)) = pv;
      }
#pragma unroll
      for (int i = 0; i < 4; ++i)
        lds[wv][kg * 4 + i][col] = a0[i] + a1[i];
    }
    __syncthreads();

    // ---- o-gate combine, h_new; tagged store, no drain; out[] after ----
    float h0v = 0.f, h1v = 0.f;
    if (tid < 128) {
      int c0i = 2 * cpr, c1i = 2 * cpr + 1;
      float s0 = lds[0][crow][c0i] + lds[1][crow][c0i] + lds[2][crow][c0i] +
                 lds[3][crow][c0i] + lds[4][crow][c0i];
      float s1 = lds[0][crow][c1i] + lds[1][crow][c1i] + lds[2][crow][c1i] +
                 lds[3][crow][c1i] + lds[4][crow][c1i];
      float o0 = sig_fast(s0), o1 = sig_fast(s1);
      h0v = o0 * tanh_fast(c_reg0);
      h1v = o1 * tanh_fast(c_reg1);
      stg_u64_sc(hUnit, pk2(h0v, h1v), (unsigned)t + 1u);   // h(t) tag t+1
    }
    bar_arrive(bar, grp, memb, 2u * t + 2u);

    if (tid < 128) {
      float2 hv; hv.x = h0v; hv.y = h1v;
      *(float2*)(out + ((size_t)t << 16) + coff) = hv;
      if (t == 511) {                    // finals: owner writes directly
        *(float2*)(out + ((size_t)512 << 16) + coff) = hv;
        float2 cv; cv.x = c_reg0; cv.y = c_reg1;
        *(float2*)(out + ((size_t)512 << 16) + 65536 + coff) = cv;
      }
    }
  }
}

extern "C" void kernel_launch(void* const* d_in, const int* in_sizes, int n_in,
                              void* d_out, int out_size, void* d_ws, size_t ws_size,
                              hipStream_t stream) {
  (void)in_sizes; (void)n_in; (void)out_size;
  const float* x  = (const float*)d_in[0];
  const float* h0 = (const float*)d_in[1];
  const float* c0 = (const float*)d_in[2];
  const float* Ww = (const float*)d_in[3];
  const float* bw = (const float*)d_in[4];
  const float* Wf = (const float*)d_in[5];
  const float* bfg= (const float*)d_in[6];
  const float* Wc = (const float*)d_in[7];
  const float* bc = (const float*)d_in[8];
  const float* Wo = (const float*)d_in[9];
  const float* bo = (const float*)d_in[10];

  if (ws_size < (size_t)WS_NEED) return;  // leaves poison -> loud failure

  prep_kernel<<<dim3(2048), dim3(256), 0, stream>>>(h0, c0, Ww, Wf, Wc, Wo,
                                                    (char*)d_ws);
  lstm_kernel<<<dim3(256), dim3(256), 0, stream>>>(x, c0, bw, bfg, bc, bo,
                                                   (float*)d_out, (char*)d_ws);
}

// Round 5
// 7415.262 us; speedup vs baseline: 1.6132x; 1.6132x over previous
//
#include <hip/hip_runtime.h>
#include <hip/hip_bf16.h>
#include <stdint.h>

// ---------------------------------------------------------------------------
// Peephole LSTM, SEQ=512, B=64, I=H=1024.  Persistent-kernel, 256 blocks.
// Round-14: R12 base (reg-pinned weights, verified 8.03ms) +
//   (1) ATOMIC-COUNTER barrier: one cumulative per-group counter replaces
//       64 member flags.  Producer: vmcnt(0) drain + __syncthreads + ONE
//       agent-scope atomicAdd (same verified ordering as R12's flag store).
//       Consumer: single lane polls one line for >= 64*epoch.  Cuts flag
//       poll traffic 64x (4096 -> 64 TCC reads/round/group) -- R12's polls
//       hot-line-thrashed TCC, inflating every RT in the sync chain.
//   (2) phase-A c-part MFMAs moved BEFORE bar_wait(h): depend only on sc_
//       (written in prev phase B, ordered by its __syncthreads).  Shortens
//       the post-wait critical path for waves 0/1.
//   (3) x(t+1) staging moved into the c-exchange gap (sx dead there;
//       arrive's __syncthreads orders vs this step's reads, bar_wait(c)'s
//       __syncthreads orders vs next step's reads).  x(0) staged at startup.
//  * R13 post-mortem: tag-validated payload regressed AGAIN (FETCH 2x,
//    retries real).  Payload must be read once, visibility guaranteed
//    BEFORE detect.  R12 exchange skeleton kept byte-identical.
// ---------------------------------------------------------------------------

typedef __attribute__((ext_vector_type(8))) short short8;
typedef __attribute__((ext_vector_type(4))) float f32x4;
typedef __attribute__((ext_vector_type(4))) unsigned int uint4v;

#define OFF_WB   25165824u   // WA: 64cg*4g*96kc*64l*8e bf16
#define OFF_HBF  27262976u   // WB: 64*4*8*64*8 bf16 = 2097152
#define OFF_CBF  27525120u   // hbf: 2 slots * 65536 bf16 = 262144
#define OFF_BAR  27787264u   // cbf: 2 slots
#define WS_NEED  27918336u   // bar: counters at 256B spacing (4 groups)

__device__ __forceinline__ short bfc(float f) {
  __hip_bfloat16 h = __float2bfloat16(f);
  return *reinterpret_cast<short*>(&h);
}
__device__ __forceinline__ unsigned pk2(float a, float b) {
  __hip_bfloat16 ha = __float2bfloat16(a), hb = __float2bfloat16(b);
  unsigned short ua = *reinterpret_cast<unsigned short*>(&ha);
  unsigned short ub = *reinterpret_cast<unsigned short*>(&hb);
  return (unsigned)ua | ((unsigned)ub << 16);
}
__device__ __forceinline__ float sig_fast(float v) {
  return __fdividef(1.f, 1.f + __expf(-v));
}
__device__ __forceinline__ float tanh_fast(float v) {
  float a = fabsf(v);
  float e = __expf(-2.f * a);
  float t = (1.f - e) * __fdividef(1.f, 1.f + e);
  return copysignf(t, v);
}

// ---- L1+L2-bypassing accesses (coherent at L3 across XCDs) ----
__device__ __forceinline__ uint4v ldg_sc(const void* p) {
  uint4v r;
  asm volatile("global_load_dwordx4 %0, %1, off sc0 sc1" : "=v"(r) : "v"(p));
  return r;
}
__device__ __forceinline__ unsigned poll_sc(const unsigned* p) {
  unsigned r;
  asm volatile("global_load_dword %0, %1, off sc0 sc1\n\ts_waitcnt vmcnt(0)"
               : "=v"(r) : "v"(p) : "memory");
  return r;
}
__device__ __forceinline__ void stg_u32_sc(unsigned* p, unsigned v) {
  asm volatile("global_store_dword %0, %1, off sc0 sc1" :: "v"(p), "v"(v) : "memory");
}

// ---- atomic-counter barrier (per 64-block rowgroup) ----
// counter dword idx: grp*64  (256 B spacing).  Cumulative: after epoch r,
// counter == 64*r.  Producer ordering identical to R12 (drain -> sync ->
// one store-class op); consumer: single lane polls one line.
__device__ __forceinline__ void bar_arrive(unsigned* bar, int grp, unsigned r) {
  (void)r;
  asm volatile("s_waitcnt vmcnt(0)" ::: "memory");   // own sc payload at L3
  __syncthreads();                                   // all waves drained
  if (threadIdx.x == 0)
    __hip_atomic_fetch_add(bar + grp * 64, 1u,
                           __ATOMIC_RELAXED, __HIP_MEMORY_SCOPE_AGENT);
}
__device__ __forceinline__ void bar_wait(unsigned* bar, int grp, unsigned r) {
  if (threadIdx.x == 0) {
    const unsigned* p = bar + grp * 64;
    const unsigned tgt = r * 64u;
    unsigned spins = 0;
    for (;;) {
      unsigned v = poll_sc(p);
      if (v >= tgt) break;
      __builtin_amdgcn_s_sleep(1);
      if (++spins > (1u << 18)) break;               // failsafe: fail loud
    }
  }
  __syncthreads();
  __builtin_amdgcn_sched_barrier(0);
}

// ---------------------------------------------------------------------------
// prep: pack weights into lane-ordered bf16 fragments + init state/barrier.
// WA slot ((cg*4+g)*96+kc)*64+l holds W_g[j=cg*16+(l&15)][kc*32+8*(l>>4)+e]
// (kc 0..31 = x, 32..63 = h, 64..95 = c; gates 2,3 only kc<64).
// WB slot ((cg*4+v)*8+kc)*64+l holds Wo[j][2048 + v*256+kc*32+8*(l>>4)+e].
// ---------------------------------------------------------------------------
#define Z0 1310720LL
#define Z1 131072LL
#define Z2 65536LL
#define Z3 32768LL

__global__ __launch_bounds__(256)
void prep_kernel(const float* __restrict__ h0, const float* __restrict__ c0,
                 const float* __restrict__ Ww, const float* __restrict__ Wf,
                 const float* __restrict__ Wc, const float* __restrict__ Wo,
                 char* __restrict__ ws) {
  __hip_bfloat16* WA  = (__hip_bfloat16*)ws;
  __hip_bfloat16* WB  = (__hip_bfloat16*)(ws + OFF_WB);
  __hip_bfloat16* hbf = (__hip_bfloat16*)(ws + OFF_HBF);
  __hip_bfloat16* cbf = (__hip_bfloat16*)(ws + OFF_CBF);
  unsigned*       bar = (unsigned*)(ws + OFF_BAR);

  const long long total = Z0 + Z1 + Z2 + Z3;
  for (long long idx = (long long)blockIdx.x * 256 + threadIdx.x; idx < total;
       idx += (long long)gridDim.x * 256) {
    if (idx < Z0) {
      int l  = (int)(idx & 63);
      int s  = (int)((idx >> 6) % 320);
      int cg = (int)(idx / (320 * 64));
      int g, kc;
      if (s < 96)       { g = 0; kc = s; }
      else if (s < 192) { g = 1; kc = s - 96; }
      else if (s < 256) { g = 2; kc = s - 192; }
      else              { g = 3; kc = s - 256; }
      int j  = cg * 16 + (l & 15);
      int kb = kc * 32 + ((l >> 4) << 3);
      const float* W; int rl;
      if (g == 0)      { W = Ww; rl = 3072; }
      else if (g == 1) { W = Wf; rl = 3072; }
      else if (g == 2) { W = Wc; rl = 2048; }
      else             { W = Wo; rl = 3072; }
      const float* src = W + (size_t)j * rl + kb;
      __hip_bfloat16* dst = WA + ((((size_t)cg * 4 + g) * 96 + kc) * 64 + l) * 8;
#pragma unroll
      for (int e = 0; e < 8; ++e) dst[e] = __float2bfloat16(src[e]);
    } else if (idx < Z0 + Z1) {
      long long q = idx - Z0;
      int l  = (int)(q & 63);
      int kc = (int)((q >> 6) & 7);
      int v  = (int)((q >> 9) & 3);
      int cg = (int)(q >> 11);
      int j  = cg * 16 + (l & 15);
      int k  = 2048 + v * 256 + kc * 32 + ((l >> 4) << 3);
      const float* src = Wo + (size_t)j * 3072 + k;
      __hip_bfloat16* dst = WB + ((((size_t)cg * 4 + v) * 8 + kc) * 64 + l) * 8;
#pragma unroll
      for (int e = 0; e < 8; ++e) dst[e] = __float2bfloat16(src[e]);
    } else if (idx < Z0 + Z1 + Z2) {
      int i = (int)(idx - (Z0 + Z1));
      hbf[i] = __float2bfloat16(h0[i]);
      cbf[i] = __float2bfloat16(c0[i]);
    } else {
      int i = (int)(idx - (Z0 + Z1 + Z2));
      bar[i] = 0u;
    }
  }
}

// ---------------------------------------------------------------------------
// main persistent kernel
// ---------------------------------------------------------------------------
__global__ __launch_bounds__(256, 1)
void lstm_kernel(const float* __restrict__ x,  const float* __restrict__ c0,
                 const float* __restrict__ bw, const float* __restrict__ bfg,
                 const float* __restrict__ bc, const float* __restrict__ bo,
                 float* __restrict__ out, char* __restrict__ ws) {
  __hip_bfloat16* hbf = (__hip_bfloat16*)(ws + OFF_HBF);
  __hip_bfloat16* cbf = (__hip_bfloat16*)(ws + OFF_CBF);
  unsigned*       bar = (unsigned*)(ws + OFF_BAR);

  const int tid  = threadIdx.x;
  const int l    = tid & 63;
  const int wv   = tid >> 6;                         // wave = gate (A) / K-split (B)
  const int b    = blockIdx.x;
  const int cg   = ((b & 7) << 3) | ((b >> 3) & 7);  // XCD-partitioned col-group
  const int grp  = b >> 6;                           // batch row-group (0..3)
  const int col  = l & 15;
  const int kg   = l >> 4;
  const int row16 = col;                             // A-frag row within tile
  const int srow  = row16 & 7;                       // LDS swizzle key
  const int j    = (cg << 4) + col;

  const float* bptr = (wv == 0) ? bw : (wv == 1) ? bfg : (wv == 2) ? bc : bo;
  const float bias = bptr[j];

  const short8* BW = (const short8*)ws + ((size_t)(cg * 4 + wv)) * 96 * 64 + l;
  const short8* BO = (const short8*)(ws + OFF_WB) + ((size_t)(cg * 4 + wv)) * 8 * 64 + l;

  __shared__ __align__(16) char sx[32768];   // x tile  [16][1024] bf16, swizzled
  __shared__ __align__(16) char sh[32768];   // h tile
  __shared__ __align__(16) char sc_[32768];  // c tile (carried across steps)
  __shared__ float lds[5][16][17];

  // combine mapping: tid<128 owns (crow, 2 cols)
  const int crow = tid >> 3;
  const int cpr  = tid & 7;
  const int coff = ((grp * 16 + crow) << 10) + (cg << 4) + 2 * cpr;
  float c_reg0 = 0.f, c_reg1 = 0.f;
  if (tid < 128) { c_reg0 = c0[coff]; c_reg1 = c0[coff + 1]; }

  // ---- startup: stage c0 tile (prep-written bf16) -> swizzled sc_ once ----
  {
    const char* csrc = (const char*)cbf + (size_t)grp * 32768;
    uint4v tc[8];
#pragma unroll
    for (int i = 0; i < 8; ++i)
      tc[i] = ldg_sc(csrc + (size_t)(i * 256 + tid) * 16);
    asm volatile("s_waitcnt vmcnt(0)" ::: "memory");
    __builtin_amdgcn_sched_barrier(0);
#pragma unroll
    for (int i = 0; i < 8; ++i) {
      int q = i * 256 + tid;
      int rw = q >> 7, kb = (q & 127) ^ (rw & 7);
      *(uint4v*)(sc_ + rw * 2048 + (kb << 4)) = tc[i];
    }
  }
  // ---- startup: stage x(0) tile (consumed by xA at t=0) ----
  {
    const float* xs = x + (size_t)grp * 16384;
#pragma unroll
    for (int i = 0; i < 8; ++i) {
      int q = i * 256 + tid;
      const float* s = xs + q * 8;
      float4 f0 = *(const float4*)s;
      float4 f1 = *(const float4*)(s + 4);
      short8 v;
      v[0] = bfc(f0.x); v[1] = bfc(f0.y); v[2] = bfc(f0.z); v[3] = bfc(f0.w);
      v[4] = bfc(f1.x); v[5] = bfc(f1.y); v[6] = bfc(f1.z); v[7] = bfc(f1.w);
      int rw = q >> 7, kb = (q & 127) ^ (rw & 7);
      *(short8*)(sx + rw * 2048 + (kb << 4)) = v;
    }
  }

  // ---- pin recurrent-path weight fragments in registers (loop-invariant) ----
  short8 WH[32];
#pragma unroll
  for (int f = 0; f < 32; ++f) WH[f] = BW[(size_t)(32 + f) * 64];
  short8 WBo[8];
#pragma unroll
  for (int k = 0; k < 8; ++k) WBo[k] = BO[(size_t)k * 64];

  __syncthreads();                     // startup sx/sc_ visible block-wide

  for (int t = 0; t < 512; ++t) {
    const int p = t & 1;
    const __hip_bfloat16* hb = hbf + (size_t)p * 65536;
    __hip_bfloat16* cbn = cbf + (size_t)(p ^ 1) * 65536;
    __hip_bfloat16* hbn = hbf + (size_t)(p ^ 1) * 65536;

    f32x4 acc[4];
#pragma unroll
    for (int u = 0; u < 4; ++u) acc[u] = (f32x4){0.f, 0.f, 0.f, 0.f};

    // ---- phase A, x part (sx staged in prev iter's c-gap / startup) ----
#pragma unroll
    for (int kc = 0; kc < 8; ++kc)
#pragma unroll
      for (int u = 0; u < 4; ++u) {
        int f = kc * 4 + u;
        short8 a = *(const short8*)(sx + row16 * 2048 + ((((f << 2) + kg) ^ srow) << 4));
        acc[u] = __builtin_amdgcn_mfma_f32_16x16x32_bf16(a, BW[(size_t)f * 64], acc[u], 0, 0, 0);
      }
    // ---- phase A, c part (write & forget gates) — BEFORE the h-wait.
    //      sc_ holds c(t-1): written in prev phase B, ordered by its
    //      __syncthreads; this step's phase B rewrites it only after
    //      multiple further barriers. ----
    if (wv < 2) {
#pragma unroll
      for (int kc = 0; kc < 8; ++kc)
#pragma unroll
        for (int u = 0; u < 4; ++u) {
          int f = kc * 4 + u;
          short8 a = *(const short8*)(sc_ + row16 * 2048 + ((((f << 2) + kg) ^ srow) << 4));
          acc[u] = __builtin_amdgcn_mfma_f32_16x16x32_bf16(a, BW[(size_t)(64 + f) * 64], acc[u], 0, 0, 0);
        }
    }

    bar_wait(bar, grp, 2u * t);          // h(t-1) visible at L3

    // ---- stage h tile: sc0/sc1 loads -> swizzled LDS ----
    {
      const char* hsrc = (const char*)hb + (size_t)grp * 32768;
      uint4v th[8];
#pragma unroll
      for (int i = 0; i < 8; ++i)
        th[i] = ldg_sc(hsrc + (size_t)(i * 256 + tid) * 16);
      asm volatile("s_waitcnt vmcnt(0)" ::: "memory");
      __builtin_amdgcn_sched_barrier(0);
#pragma unroll
      for (int i = 0; i < 8; ++i) {
        int q = i * 256 + tid;
        int rw = q >> 7, kb = (q & 127) ^ (rw & 7);
        *(uint4v*)(sh + rw * 2048 + (kb << 4)) = th[i];
      }
    }
    __syncthreads();

    // ---- phase A, h part (all gates) — register-pinned fragments ----
#pragma unroll
    for (int kc = 0; kc < 8; ++kc)
#pragma unroll
      for (int u = 0; u < 4; ++u) {
        int f = kc * 4 + u;
        short8 a = *(const short8*)(sh + row16 * 2048 + ((((f << 2) + kg) ^ srow) << 4));
        acc[u] = __builtin_amdgcn_mfma_f32_16x16x32_bf16(a, WH[f], acc[u], 0, 0, 0);
      }
    {
      const int dbuf = (wv == 3) ? 4 : wv;
#pragma unroll
      for (int i = 0; i < 4; ++i)
        lds[dbuf][kg * 4 + i][col] = acc[0][i] + acc[1][i] + acc[2][i] + acc[3][i] + bias;
    }
    __syncthreads();

    // ---- c_new combine (tid<128: 2 elems each) ----
    if (tid < 128) {
      float aw0 = lds[0][crow][2 * cpr], aw1 = lds[0][crow][2 * cpr + 1];
      float af0 = lds[1][crow][2 * cpr], af1 = lds[1][crow][2 * cpr + 1];
      float ag0 = lds[2][crow][2 * cpr], ag1 = lds[2][crow][2 * cpr + 1];
      float cn0 = sig_fast(af0) * c_reg0 + sig_fast(aw0) * tanh_fast(ag0);
      float cn1 = sig_fast(af1) * c_reg1 + sig_fast(aw1) * tanh_fast(ag1);
      c_reg0 = cn0; c_reg1 = cn1;
      stg_u32_sc((unsigned*)((char*)cbn + 2 * (size_t)coff), pk2(cn0, cn1));
    }
    bar_arrive(bar, grp, 2u * t + 1u);

    // ---- fill the c-exchange gap: stage x(t+1) (sx is dead here; the
    //      arrive's __syncthreads ordered it vs this step's xA reads) ----
    if (t < 511) {
      const float* xs = x + (((size_t)t + 1) << 16) + (size_t)grp * 16384;
#pragma unroll
      for (int i = 0; i < 8; ++i) {
        int q = i * 256 + tid;
        const float* s = xs + q * 8;
        float4 f0 = *(const float4*)s;
        float4 f1 = *(const float4*)(s + 4);
        short8 v;
        v[0] = bfc(f0.x); v[1] = bfc(f0.y); v[2] = bfc(f0.z); v[3] = bfc(f0.w);
        v[4] = bfc(f1.x); v[5] = bfc(f1.y); v[6] = bfc(f1.z); v[7] = bfc(f1.w);
        int rw = q >> 7, kb = (q & 127) ^ (rw & 7);
        *(short8*)(sx + rw * 2048 + (kb << 4)) = v;
      }
    }

    bar_wait(bar, grp, 2u * t + 1u);     // c_new visible

    // ---- phase B: o += c_new @ Woc^T (wave = K-split); also carry c_new
    //      into sc_ (swizzled) as next step's c(t-1) tile ----
    {
      f32x4 a0 = {0.f, 0.f, 0.f, 0.f}, a1 = {0.f, 0.f, 0.f, 0.f};
      const char* cbase = (const char*)cbn + (size_t)(grp * 16 + row16) * 2048 +
                          (size_t)wv * 512 + (size_t)kg * 16;
      uint4v ca[8];
#pragma unroll
      for (int kcc = 0; kcc < 8; ++kcc) ca[kcc] = ldg_sc(cbase + kcc * 64);
      asm volatile("s_waitcnt vmcnt(0)" ::: "memory");
      __builtin_amdgcn_sched_barrier(0);
#pragma unroll
      for (int kcc = 0; kcc < 8; ++kcc) {
        short8 a = __builtin_bit_cast(short8, ca[kcc]);
        if (kcc & 1) a1 = __builtin_amdgcn_mfma_f32_16x16x32_bf16(a, WBo[kcc], a1, 0, 0, 0);
        else         a0 = __builtin_amdgcn_mfma_f32_16x16x32_bf16(a, WBo[kcc], a0, 0, 0, 0);
      }
      // carry write: units u = wv*32 + kg + kcc*4 cover 0..127 bijectively
      // across (wv,kg,kcc); reads of sc_ happen next step (ordered by syncs).
      const int ub = wv * 32 + kg;
#pragma unroll
      for (int kcc = 0; kcc < 8; ++kcc)
        *(uint4v*)(sc_ + row16 * 2048 + (((ub + kcc * 4) ^ srow) << 4)) = ca[kcc];
#pragma unroll
      for (int i = 0; i < 4; ++i)
        lds[wv][kg * 4 + i][col] = a0[i] + a1[i];
    }
    __syncthreads();

    // ---- o-gate combine, h_new; hbn (payload) BEFORE arrive, out[] AFTER ----
    float h0v = 0.f, h1v = 0.f;
    if (tid < 128) {
      int c0i = 2 * cpr, c1i = 2 * cpr + 1;
      float s0 = lds[0][crow][c0i] + lds[1][crow][c0i] + lds[2][crow][c0i] +
                 lds[3][crow][c0i] + lds[4][crow][c0i];
      float s1 = lds[0][crow][c1i] + lds[1][crow][c1i] + lds[2][crow][c1i] +
                 lds[3][crow][c1i] + lds[4][crow][c1i];
      float o0 = sig_fast(s0), o1 = sig_fast(s1);
      h0v = o0 * tanh_fast(c_reg0);
      h1v = o1 * tanh_fast(c_reg1);
      stg_u32_sc((unsigned*)((char*)hbn + 2 * (size_t)coff), pk2(h0v, h1v));
    }
    bar_arrive(bar, grp, 2u * t + 2u);

    if (tid < 128) {
      float2 hv; hv.x = h0v; hv.y = h1v;
      *(float2*)(out + ((size_t)t << 16) + coff) = hv;
      if (t == 511) {                    // finals: owner writes directly
        *(float2*)(out + ((size_t)512 << 16) + coff) = hv;
        float2 cv; cv.x = c_reg0; cv.y = c_reg1;
        *(float2*)(out + ((size_t)512 << 16) + 65536 + coff) = cv;
      }
    }
  }
}

extern "C" void kernel_launch(void* const* d_in, const int* in_sizes, int n_in,
                              void* d_out, int out_size, void* d_ws, size_t ws_size,
                              hipStream_t stream) {
  (void)in_sizes; (void)n_in; (void)out_size;
  const float* x  = (const float*)d_in[0];
  const float* h0 = (const float*)d_in[1];
  const float* c0 = (const float*)d_in[2];
  const float* Ww = (const float*)d_in[3];
  const float* bw = (const float*)d_in[4];
  const float* Wf = (const float*)d_in[5];
  const float* bfg= (const float*)d_in[6];
  const float* Wc = (const float*)d_in[7];
  const float* bc = (const float*)d_in[8];
  const float* Wo = (const float*)d_in[9];
  const float* bo = (const float*)d_in[10];

  if (ws_size < (size_t)WS_NEED) return;  // leaves poison -> loud failure

  prep_kernel<<<dim3(2048), dim3(256), 0, stream>>>(h0, c0, Ww, Wf, Wc, Wo,
                                                    (char*)d_ws);
  lstm_kernel<<<dim3(256), dim3(256), 0, stream>>>(x, c0, bw, bfg, bc, bo,
                                                   (float*)d_out, (char*)d_ws);
}